// Round 13
// baseline (82.649 us; speedup 1.0000x reference)
//
#include <hip/hip_runtime.h>
#include <hip/hip_bf16.h>

#define B_    32
#define H_    256
#define W_    256
#define ROWS  8            // output rows per tile
#define LR    (ROWS + 2)   // 10 LDS rows (halo)
#define LCP   68           // padded cols -> row stride 136 16B-units (mult of 8 keeps XOR bijective)
#define RSTR  (LCP*2)      // 136 units per row
#define BUFU  (LR*RSTR)    // 1360 s16x8 units per LDS quant buffer
#define NT    8            // tiles per block (vertically adjacent; hg start mod 32 in {0,8,16,24})
#define NTILES (B_*(H_/ROWS)*(W_/64))   // 4096
#define RAWB  (128*64)     // raw body floats: 128 planes x 64 cols
#define RAWH  256          // raw halo floats
// ws layout: [64,5184)=packA | [8192,16384)=pmax[2048] floats

typedef float f32x4 __attribute__((ext_vector_type(4)));
typedef short s16x8 __attribute__((ext_vector_type(8)));
typedef unsigned int u32;

__device__ inline unsigned short f2bf(float f){
  __hip_bfloat16 h = __float2bfloat16(f);
  return __builtin_bit_cast(unsigned short, h);
}

// exact round-half-even of x/s via reciprocal + exact fma residual correction
__device__ inline float quant1(float v, float rinv, float s, float hs){
  float q0 = rintf(v * rinv);
  float d  = fmaf(q0, -s, v);        // ~ s*(v/s - q0), one rounding
  q0 += (d >  hs) ? 1.f : 0.f;
  q0 -= (d < -hs) ? 1.f : 0.f;
  return fminf(fmaxf(q0, -127.f), 127.f);
}

// tile id t: hg fastest (consecutive tiles vertically adjacent), then strip, b
__device__ __forceinline__ void tile_decode(int t, int& b, int& w0, int& h0){
  int hg = t & 31; int r = t >> 5;
  w0 = (r & 3) * 64; b = r >> 2; h0 = hg * ROWS;
}

__device__ __forceinline__ void build_packA(const float* __restrict__ wq,
                                            unsigned short* __restrict__ packA,
                                            int l){
  int co = l & 15;
  int g  = l >> 4;
  for (int mm2 = 0; mm2 < 5; ++mm2){
    for (int i = 0; i < 8; ++i){
      int kappa = g*8 + i;
      int tap = 2*mm2 + (kappa >> 4);
      int ci  = kappa & 15;
      float v = (tap <= 8) ? wq[(co*16 + ci)*9 + tap] : 0.f;
      packA[(mm2*64 + l)*8 + i] = f2bf(v);
    }
  }
}

// --- kernel 1: per-block max|x| -> pmax[bid] + packA build in block 0 (r8) ---
__global__ __launch_bounds__(256) void absmax_kernel(const float* __restrict__ x,
                                                     const float* __restrict__ wq,
                                                     float* __restrict__ pmax,
                                                     unsigned short* __restrict__ packA,
                                                     int n4){
  __shared__ float red[4];
  int idx = blockIdx.x*blockDim.x + threadIdx.x;
  int stride = gridDim.x*blockDim.x;
  float m = 0.f;
  for (int i = idx; i < n4; i += stride){
    float4 v = reinterpret_cast<const float4*>(x)[i];
    m = fmaxf(m, fmaxf(fmaxf(fabsf(v.x), fabsf(v.y)), fmaxf(fabsf(v.z), fabsf(v.w))));
  }
  #pragma unroll
  for (int off = 32; off > 0; off >>= 1)
    m = fmaxf(m, __shfl_xor(m, off));
  int lane = threadIdx.x & 63, wid = threadIdx.x >> 6;
  if (lane == 0) red[wid] = m;
  __syncthreads();
  if (threadIdx.x == 0)
    pmax[blockIdx.x] = fmaxf(fmaxf(red[0], red[1]), fmaxf(red[2], red[3]));
  if (blockIdx.x == 0 && threadIdx.x < 64) build_packA(wq, packA, threadIdx.x);
}

// ---- prologue Q helpers (register path, verified r8-r12), full 20-group tile ----
__device__ __forceinline__ void q_load_full(const float* __restrict__ x,
                                            int b, int w0, int h0,
                                            int tid, int lane, int wid,
                                            float v[3][8], float tv[8]){
  const int c = lane;
  const int win = w0 - 1 + c;
  const bool colok = (unsigned)win < 256u;
  #pragma unroll
  for (int k = 0; k < 3; ++k){
    int gi = wid + 8*k;
    bool act = gi < 20;
    int r = gi >> 1, half = gi & 1;
    int hin = h0 + r - 1;
    bool rowok = (unsigned)hin < 256u;
    bool ok = act && rowok && colok;
    const float* p = x + ((size_t)(b*16 + half*8) << 16) + (size_t)(rowok ? hin : 0)*256 + win;
    #pragma unroll
    for (int ci = 0; ci < 8; ++ci)
      v[k][ci] = ok ? p[(size_t)ci << 16] : 0.f;
  }
  if (tid >= 448 && tid < 488){
    int t = tid - 448;
    int t_c = 64 + (t & 1), t_half = (t >> 1) & 1, t_r = t >> 2;
    int hin = h0 + t_r - 1;
    bool rowok = (unsigned)hin < 256u;
    int twin = w0 - 1 + t_c;
    bool ok = rowok && ((unsigned)twin < 256u);
    const float* p = x + ((size_t)(b*16 + t_half*8) << 16) + (size_t)(rowok ? hin : 0)*256 + twin;
    #pragma unroll
    for (int ci = 0; ci < 8; ++ci)
      tv[ci] = ok ? p[(size_t)ci << 16] : 0.f;
  }
}

__device__ __forceinline__ void q_write_full(s16x8* ldsv,
                                             int tid, int lane, int wid,
                                             const float v[3][8], const float tv[8],
                                             float rinv, float s, float hs){
  const int c = lane;
  #pragma unroll
  for (int k = 0; k < 3; ++k){
    int gi = wid + 8*k;
    if (gi < 20){
      int r = gi >> 1, half = gi & 1;
      s16x8 qv;
      #pragma unroll
      for (int ci = 0; ci < 8; ++ci)
        qv[ci] = (short)f2bf(quant1(v[k][ci], rinv, s, hs));
      int u = (r*RSTR + c*2 + half) ^ ((c >> 2) & 7);
      ldsv[u] = qv;
    }
  }
  if (tid >= 448 && tid < 488){
    int t = tid - 448;
    int t_c = 64 + (t & 1), t_half = (t >> 1) & 1, t_r = t >> 2;
    s16x8 qv;
    #pragma unroll
    for (int ci = 0; ci < 8; ++ci)
      qv[ci] = (short)f2bf(quant1(tv[ci], rinv, s, hs));
    int u = (t_r*RSTR + t_c*2 + t_half) ^ ((t_c >> 2) & 7);
    ldsv[u] = qv;
  }
}

// ---- async raw staging (HBM -> LDS DMA, zero VGPR in flight) ----
// body: wave wid stages row rr=wid, plane p = wid*16+ci, 64 cols (w0..w0+63).
// halo: waves 0..3 stage 64 elems each: e = wid*64+lane, p=e>>1, side=e&1.
// OOB rows/cols use CLAMPED addresses; masking happens at quant time.
__device__ __forceinline__ void dma_stage(const float* __restrict__ x,
                                          int b, int w0, int h02,
                                          int lane, int wid, u32* raw){
  int hin2 = h02 + wid + 1;
  int hinc = hin2 > 255 ? 255 : hin2;
  #pragma unroll
  for (int ci = 0; ci < 16; ++ci){
    const float* g = x + ((size_t)(b*16 + ci) << 16) + (size_t)hinc*256 + (w0 + lane);
    __builtin_amdgcn_global_load_lds(
        (const __attribute__((address_space(1))) u32*)g,
        (__attribute__((address_space(3))) u32*)(raw + (wid*16 + ci)*64), 4, 0, 0);
  }
  if (wid < 4){
    int e = wid*64 + lane;
    int p = e >> 1, side = e & 1;
    int rr = p >> 4, ci = p & 15;
    int hh = h02 + rr + 1; hh = hh > 255 ? 255 : hh;
    int win2 = side ? (w0 + 64) : (w0 - 1);
    win2 = win2 < 0 ? 0 : (win2 > 255 ? 255 : win2);
    const float* g = x + ((size_t)(b*16 + ci) << 16) + (size_t)hh*256 + win2;
    __builtin_amdgcn_global_load_lds(
        (const __attribute__((address_space(1))) u32*)g,
        (__attribute__((address_space(3))) u32*)(raw + RAWB + wid*64), 4, 0, 0);
  }
}

// ---- quant from raw LDS into swizzled quant buffer (rows 2..9) ----
__device__ __forceinline__ void quant_pair(s16x8* ldsq, int bufoff, const u32* raw,
                                           int rr, int c, int half, bool rowok, int w0,
                                           float rinv, float s, float hs){
  bool ok = rowok && (c == 0 ? (w0 > 0) : (c == 65 ? (w0 < 192) : true));
  s16x8 qv;
  #pragma unroll
  for (int i = 0; i < 8; ++i){
    int ci = half*8 + i;
    int p  = rr*16 + ci;
    u32 bits = (c >= 1 && c <= 64) ? raw[p*64 + (c - 1)]
                                   : raw[RAWB + p*2 + (c != 0)];
    float val = ok ? __uint_as_float(bits) : 0.f;
    qv[i] = (short)f2bf(quant1(val, rinv, s, hs));
  }
  int r = rr + 2;
  int u = (r*RSTR + c*2 + half) ^ ((c >> 2) & 7);
  ldsq[bufoff + u] = qv;
}

__device__ __forceinline__ void quant_from_raw(s16x8* ldsq, int bufoff, const u32* raw,
                                               int lane, int wid, int w0, int h02,
                                               float rinv, float s, float hs){
  const int rr = wid;
  const bool rowok = (h02 + rr + 1) < 256;
  quant_pair(ldsq, bufoff, raw, rr, lane, 0, rowok, w0, rinv, s, hs);
  quant_pair(ldsq, bufoff, raw, rr, lane, 1, rowok, w0, rinv, s, hs);
  if (lane < 4)
    quant_pair(ldsq, bufoff, raw, rr, 64 + (lane >> 1), lane & 1, rowok, w0, rinv, s, hs);
}

// ---- C phase: one output row per wave, 4 col-chunks x 5 MFMAs (verified r6-12)
__device__ __forceinline__ void c_phase(const s16x8* ldsv, int bufoff,
                                        const s16x8 A[5], const int kr[5], const int kw[5],
                                        int lane, int wid, int b, int w0, int h0,
                                        const float sc[4], const float bb[4],
                                        float* __restrict__ out){
  const int colg = lane & 15;
  const int g    = lane >> 4;
  const int hlf  = g & 1;
  f32x4 acc[4] = {};
  #pragma unroll
  for (int n = 0; n < 4; ++n){
    #pragma unroll
    for (int m = 0; m < 5; ++m){
      int cc = n*16 + colg + kw[m];
      int u = ((wid + kr[m])*RSTR + cc*2 + hlf) ^ ((cc >> 2) & 7);
      acc[n] = __builtin_amdgcn_mfma_f32_16x16x32_bf16(A[m], ldsv[bufoff + u], acc[n], 0, 0, 0);
    }
  }
  const int h = h0 + wid;
  #pragma unroll
  for (int j = 0; j < 4; ++j){
    const int co = g*4 + j;
    float* op = out + ((size_t)(b*16 + co) << 16) + h*256 + w0 + colg;
    #pragma unroll
    for (int n = 0; n < 4; ++n)
      __builtin_nontemporal_store(acc[n][j] * sc[j] + bb[j], op + n*16);
  }
}

// --- kernel 2: persistent fused quant+conv; next-tile raw staged by
// global_load_lds DMA (in flight across c_phase, zero VGPR), then quantized
// LDS->LDS. Separate __shared__ objects so alias analysis can't inject waits.
__global__ __launch_bounds__(512)
void fconv_kernel(const float* __restrict__ x,
                  const float* __restrict__ sw,
                  const float* __restrict__ bias,
                  const float* __restrict__ pmax,
                  const unsigned short* __restrict__ packA,
                  float* __restrict__ out){
  __shared__ __align__(16) unsigned short lds_q[2*LR*LCP*16];
  __shared__ __align__(16) u32 lds_raw[RAWB + RAWH];
  __shared__ float redmax[8];
  s16x8* ldsq = reinterpret_cast<s16x8*>(lds_q);

  const int tid  = threadIdx.x;
  const int lane = tid & 63;
  const int wid  = tid >> 6;     // 0..7

  const int bid = blockIdx.x;
  const int t0  = (bid & 7)*512 + (bid >> 3)*NT;   // XCD-chunked, bijective

  int b, w0, h0;
  float v[3][8], tv[8];

  // prologue tile t0: register-path loads FIRST (pmax reduce hides under them)
  tile_decode(t0, b, w0, h0);
  q_load_full(x, b, w0, h0, tid, lane, wid, v, tv);

  // global-max reduce over 2048 partials (8KB, L2-resident)
  float4 pv = reinterpret_cast<const float4*>(pmax)[tid];
  float m = fmaxf(fmaxf(pv.x, pv.y), fmaxf(pv.z, pv.w));
  #pragma unroll
  for (int off = 32; off > 0; off >>= 1)
    m = fmaxf(m, __shfl_xor(m, off));
  if (lane == 0) redmax[wid] = m;
  __syncthreads();
  float gm = redmax[0];
  #pragma unroll
  for (int i = 1; i < 8; ++i) gm = fmaxf(gm, redmax[i]);

  const float s    = gm * 0.0078125f;   // max|x| / 128
  const float rinv = 1.0f / s;
  const float hs   = 0.5f * s;

  // loop-invariant A fragments, tap geometry, dequant constants
  const int g   = lane >> 4;
  const int tlg = g >> 1;
  int kr[5], kw[5];
  #pragma unroll
  for (int mm = 0; mm < 5; ++mm){
    int t = 2*mm + tlg; if (t > 8) t = 8;  // tap 9: A=0, read tap 8 (finite)
    kr[mm] = (t*11) >> 5;
    kw[mm] = t - kr[mm]*3;
  }
  s16x8 A[5];
  const s16x8* pA = reinterpret_cast<const s16x8*>(packA);
  #pragma unroll
  for (int mm = 0; mm < 5; ++mm) A[mm] = pA[mm*64 + lane];
  float sc[4], bb[4];
  #pragma unroll
  for (int j = 0; j < 4; ++j){
    sc[j] = s * sw[g*4 + j];
    bb[j] = bias[g*4 + j];
  }

  q_write_full(ldsq, tid, lane, wid, v, tv, rinv, s, hs);
  __syncthreads();

  for (int k = 0; k < NT; ++k){
    const int cur = k & 1;
    if (k < NT-1){
      int b2, w2, h2; tile_decode(t0 + k + 1, b2, w2, h2);
      dma_stage(x, b2, w2, h2, lane, wid, lds_raw);   // async, in flight across c_phase
    }
    tile_decode(t0 + k, b, w0, h0);
    c_phase(ldsq, cur*BUFU, A, kr, kw, lane, wid, b, w0, h0, sc, bb, out);
    if (k < NT-1){
      __syncthreads();   // barrier A: vmcnt(0) drain completes the DMAs; cross-wave visible
      // halo-row reuse: tile k rows 8,9 == tile k+1 rows 0,1 (swizzle row-local)
      if (tid < 2*RSTR){
        int rr2 = tid >= RSTR;
        int cc2 = tid - rr2*RSTR;
        ldsq[(cur^1)*BUFU + rr2*RSTR + cc2] = ldsq[cur*BUFU + (8+rr2)*RSTR + cc2];
      }
      int b2, w2, h2; tile_decode(t0 + k + 1, b2, w2, h2);
      quant_from_raw(ldsq, (cur^1)*BUFU, lds_raw, lane, wid, w2, h2, rinv, s, hs);
      __syncthreads();   // barrier B: quant buffer ready for next c_phase
    }
  }
}

extern "C" void kernel_launch(void* const* d_in, const int* in_sizes, int n_in,
                              void* d_out, int out_size, void* d_ws, size_t ws_size,
                              hipStream_t stream){
  const float* x    = (const float*)d_in[0];
  const float* wq   = (const float*)d_in[1];
  const float* sw   = (const float*)d_in[2];
  const float* bias = (const float*)d_in[3];
  float* out = (float*)d_out;
  unsigned short* packA = (unsigned short*)((char*)d_ws + 64);
  float* pmax = (float*)((char*)d_ws + 8192);

  absmax_kernel<<<2048, 256, 0, stream>>>(x, wq, pmax, packA, (B_*16*H_*W_)/4);
  fconv_kernel<<<NTILES/NT, 512, 0, stream>>>(x, sw, bias, pmax, packA, out);
}

// Round 14
// 77.508 us; speedup vs baseline: 1.0663x; 1.0663x over previous
//
#include <hip/hip_runtime.h>
#include <hip/hip_bf16.h>

#define B_    32
#define H_    256
#define W_    256
#define ROWS  8            // output rows per tile
#define LR    (ROWS + 2)   // 10 LDS rows (halo)
#define LCP   68           // padded cols -> row stride 136 16B-units (mult of 8 keeps XOR bijective)
#define RSTR  (LCP*2)      // 136 units per row
#define BUFU  (LR*RSTR)    // 1360 s16x8 units per LDS quant buffer
#define NT    8            // tiles per block (vertically adjacent; hg start mod 32 in {0,8,16,24})
#define NTILES (B_*(H_/ROWS)*(W_/64))   // 4096
#define RAWB  (128*64)     // raw body floats: 128 planes x 64 cols
#define RAWH  256          // raw halo floats
// ws layout: [64,5184)=packA | [8192,16384)=pmax[2048] floats

typedef float f32x4 __attribute__((ext_vector_type(4)));
typedef short s16x8 __attribute__((ext_vector_type(8)));
typedef unsigned int u32;

__device__ inline unsigned short f2bf(float f){
  __hip_bfloat16 h = __float2bfloat16(f);
  return __builtin_bit_cast(unsigned short, h);
}

// exact round-half-even of x/s via reciprocal + exact fma residual correction
__device__ inline float quant1(float v, float rinv, float s, float hs){
  float q0 = rintf(v * rinv);
  float d  = fmaf(q0, -s, v);        // ~ s*(v/s - q0), one rounding
  q0 += (d >  hs) ? 1.f : 0.f;
  q0 -= (d < -hs) ? 1.f : 0.f;
  return fminf(fmaxf(q0, -127.f), 127.f);
}

// tile id t: hg fastest (consecutive tiles vertically adjacent), then strip, b
__device__ __forceinline__ void tile_decode(int t, int& b, int& w0, int& h0){
  int hg = t & 31; int r = t >> 5;
  w0 = (r & 3) * 64; b = r >> 2; h0 = hg * ROWS;
}

__device__ __forceinline__ void build_packA(const float* __restrict__ wq,
                                            unsigned short* __restrict__ packA,
                                            int l){
  int co = l & 15;
  int g  = l >> 4;
  for (int mm2 = 0; mm2 < 5; ++mm2){
    for (int i = 0; i < 8; ++i){
      int kappa = g*8 + i;
      int tap = 2*mm2 + (kappa >> 4);
      int ci  = kappa & 15;
      float v = (tap <= 8) ? wq[(co*16 + ci)*9 + tap] : 0.f;
      packA[(mm2*64 + l)*8 + i] = f2bf(v);
    }
  }
}

// --- kernel 1: per-block max|x| -> pmax[bid] + packA build in block 0 (r8) ---
__global__ __launch_bounds__(256) void absmax_kernel(const float* __restrict__ x,
                                                     const float* __restrict__ wq,
                                                     float* __restrict__ pmax,
                                                     unsigned short* __restrict__ packA,
                                                     int n4){
  __shared__ float red[4];
  int idx = blockIdx.x*blockDim.x + threadIdx.x;
  int stride = gridDim.x*blockDim.x;
  float m = 0.f;
  for (int i = idx; i < n4; i += stride){
    float4 v = reinterpret_cast<const float4*>(x)[i];
    m = fmaxf(m, fmaxf(fmaxf(fabsf(v.x), fabsf(v.y)), fmaxf(fabsf(v.z), fabsf(v.w))));
  }
  #pragma unroll
  for (int off = 32; off > 0; off >>= 1)
    m = fmaxf(m, __shfl_xor(m, off));
  int lane = threadIdx.x & 63, wid = threadIdx.x >> 6;
  if (lane == 0) red[wid] = m;
  __syncthreads();
  if (threadIdx.x == 0)
    pmax[blockIdx.x] = fmaxf(fmaxf(red[0], red[1]), fmaxf(red[2], red[3]));
  if (blockIdx.x == 0 && threadIdx.x < 64) build_packA(wq, packA, threadIdx.x);
}

// ---- prologue Q helpers (register path, verified r8-r13), full 20-group tile ----
__device__ __forceinline__ void q_load_full(const float* __restrict__ x,
                                            int b, int w0, int h0,
                                            int tid, int lane, int wid,
                                            float v[3][8], float tv[8]){
  const int c = lane;
  const int win = w0 - 1 + c;
  const bool colok = (unsigned)win < 256u;
  #pragma unroll
  for (int k = 0; k < 3; ++k){
    int gi = wid + 8*k;
    bool act = gi < 20;
    int r = gi >> 1, half = gi & 1;
    int hin = h0 + r - 1;
    bool rowok = (unsigned)hin < 256u;
    bool ok = act && rowok && colok;
    const float* p = x + ((size_t)(b*16 + half*8) << 16) + (size_t)(rowok ? hin : 0)*256 + win;
    #pragma unroll
    for (int ci = 0; ci < 8; ++ci)
      v[k][ci] = ok ? p[(size_t)ci << 16] : 0.f;
  }
  if (tid >= 448 && tid < 488){
    int t = tid - 448;
    int t_c = 64 + (t & 1), t_half = (t >> 1) & 1, t_r = t >> 2;
    int hin = h0 + t_r - 1;
    bool rowok = (unsigned)hin < 256u;
    int twin = w0 - 1 + t_c;
    bool ok = rowok && ((unsigned)twin < 256u);
    const float* p = x + ((size_t)(b*16 + t_half*8) << 16) + (size_t)(rowok ? hin : 0)*256 + twin;
    #pragma unroll
    for (int ci = 0; ci < 8; ++ci)
      tv[ci] = ok ? p[(size_t)ci << 16] : 0.f;
  }
}

__device__ __forceinline__ void q_write_full(s16x8* ldsv,
                                             int tid, int lane, int wid,
                                             const float v[3][8], const float tv[8],
                                             float rinv, float s, float hs){
  const int c = lane;
  #pragma unroll
  for (int k = 0; k < 3; ++k){
    int gi = wid + 8*k;
    if (gi < 20){
      int r = gi >> 1, half = gi & 1;
      s16x8 qv;
      #pragma unroll
      for (int ci = 0; ci < 8; ++ci)
        qv[ci] = (short)f2bf(quant1(v[k][ci], rinv, s, hs));
      int u = (r*RSTR + c*2 + half) ^ ((c >> 2) & 7);
      ldsv[u] = qv;
    }
  }
  if (tid >= 448 && tid < 488){
    int t = tid - 448;
    int t_c = 64 + (t & 1), t_half = (t >> 1) & 1, t_r = t >> 2;
    s16x8 qv;
    #pragma unroll
    for (int ci = 0; ci < 8; ++ci)
      qv[ci] = (short)f2bf(quant1(tv[ci], rinv, s, hs));
    int u = (t_r*RSTR + t_c*2 + t_half) ^ ((t_c >> 2) & 7);
    ldsv[u] = qv;
  }
}

// ---- async raw staging, 16B-wide body DMA (4 insts/wave), 4B halo ----
// body plane p = wid*16 + i*4 + (lane>>4), cols 4*(lane&15)..+3 (clamped rows).
// halo: waves 0..3, 1 inst: e = wid*64+lane -> raw[RAWB + e], e = p*2 + side.
__device__ __forceinline__ void dma_stage16(const float* __restrict__ x,
                                            int b, int w0, int h02,
                                            int lane, int wid, u32* raw){
  int hin2 = h02 + wid + 1;
  int hinc = hin2 > 255 ? 255 : hin2;
  int sub  = lane >> 4;
  int c4   = (lane & 15) * 4;
  #pragma unroll
  for (int i = 0; i < 4; ++i){
    int ci = i*4 + sub;
    const float* g = x + ((size_t)(b*16 + ci) << 16) + (size_t)hinc*256 + (w0 + c4);
    __builtin_amdgcn_global_load_lds(
        (const __attribute__((address_space(1))) u32*)g,
        (__attribute__((address_space(3))) u32*)(raw + (wid*16 + i*4)*64), 16, 0, 0);
  }
  if (wid < 4){
    int e = wid*64 + lane;
    int p = e >> 1, side = e & 1;
    int rr = p >> 4, ci = p & 15;
    int hh = h02 + rr + 1; hh = hh > 255 ? 255 : hh;
    int win2 = side ? (w0 + 64) : (w0 - 1);
    win2 = win2 < 0 ? 0 : (win2 > 255 ? 255 : win2);
    const float* g = x + ((size_t)(b*16 + ci) << 16) + (size_t)hh*256 + win2;
    __builtin_amdgcn_global_load_lds(
        (const __attribute__((address_space(1))) u32*)g,
        (__attribute__((address_space(3))) u32*)(raw + RAWB + wid*64), 4, 0, 0);
  }
}

// ---- tail quant (cols 64,65) straight from raw LDS (r13-verified indexing) ----
__device__ __forceinline__ void quant_pair(s16x8* ldsq, int bufoff, const u32* raw,
                                           int rr, int c, int half, bool rowok, int w0,
                                           float rinv, float s, float hs){
  bool ok = rowok && (c == 0 ? (w0 > 0) : (c == 65 ? (w0 < 192) : true));
  s16x8 qv;
  #pragma unroll
  for (int i = 0; i < 8; ++i){
    int ci = half*8 + i;
    int p  = rr*16 + ci;
    u32 bits = (c >= 1 && c <= 64) ? raw[p*64 + (c - 1)]
                                   : raw[RAWB + p*2 + (c != 0)];
    float val = ok ? __uint_as_float(bits) : 0.f;
    qv[i] = (short)f2bf(quant1(val, rinv, s, hs));
  }
  int r = rr + 2;
  int u = (r*RSTR + c*2 + half) ^ ((c >> 2) & 7);
  ldsq[bufoff + u] = qv;
}

// ---- main-col quant from the register snapshot (c = lane, rows 2..9) ----
__device__ __forceinline__ void quant_main_regs(s16x8* ldsq, int bufoff,
                                                const u32 r[16], int lane, int wid,
                                                int w2, int h2,
                                                float rinv, float s, float hs){
  const bool rowok = (h2 + wid + 1) < 256;
  const bool ok = rowok && (lane > 0 ? true : (w2 > 0));
  #pragma unroll
  for (int half = 0; half < 2; ++half){
    s16x8 qv;
    #pragma unroll
    for (int i = 0; i < 8; ++i){
      float val = ok ? __uint_as_float(r[half*8 + i]) : 0.f;
      qv[i] = (short)f2bf(quant1(val, rinv, s, hs));
    }
    int u = ((wid + 2)*RSTR + lane*2 + half) ^ ((lane >> 2) & 7);
    ldsq[bufoff + u] = qv;
  }
}

// ---- C phase: one output row per wave, 4 col-chunks x 5 MFMAs (verified r6-13).
// Exactly 16 un-mergeable dword stores per thread (vmcnt(16) counts on this).
__device__ __forceinline__ void c_phase(const s16x8* ldsv, int bufoff,
                                        const s16x8 A[5], const int kr[5], const int kw[5],
                                        int lane, int wid, int b, int w0, int h0,
                                        const float sc[4], const float bb[4],
                                        float* __restrict__ out){
  const int colg = lane & 15;
  const int g    = lane >> 4;
  const int hlf  = g & 1;
  f32x4 acc[4] = {};
  #pragma unroll
  for (int n = 0; n < 4; ++n){
    #pragma unroll
    for (int m = 0; m < 5; ++m){
      int cc = n*16 + colg + kw[m];
      int u = ((wid + kr[m])*RSTR + cc*2 + hlf) ^ ((cc >> 2) & 7);
      acc[n] = __builtin_amdgcn_mfma_f32_16x16x32_bf16(A[m], ldsv[bufoff + u], acc[n], 0, 0, 0);
    }
  }
  const int h = h0 + wid;
  #pragma unroll
  for (int j = 0; j < 4; ++j){
    const int co = g*4 + j;
    float* op = out + ((size_t)(b*16 + co) << 16) + h*256 + w0 + colg;
    #pragma unroll
    for (int n = 0; n < 4; ++n)
      __builtin_nontemporal_store(acc[n][j] * sc[j] + bb[j], op + n*16);
  }
}

// --- kernel 2: persistent quant+conv with COUNTED-vmcnt pipeline (T4):
// DMA(k+2) issued before quant(k+1) compute and kept in flight across raw
// s_barriers (lgkm-only) and the whole next c_phase. vmcnt(16) leaves the 16
// output stores outstanding while draining the (older) DMAs.
__global__ __launch_bounds__(512)
void fconv_kernel(const float* __restrict__ x,
                  const float* __restrict__ sw,
                  const float* __restrict__ bias,
                  const float* __restrict__ pmax,
                  const unsigned short* __restrict__ packA,
                  float* __restrict__ out){
  __shared__ __align__(16) unsigned short lds_q[2*LR*LCP*16];
  __shared__ __align__(16) u32 lds_raw[RAWB + RAWH];
  __shared__ float redmax[8];
  s16x8* ldsq = reinterpret_cast<s16x8*>(lds_q);

  const int tid  = threadIdx.x;
  const int lane = tid & 63;
  const int wid  = tid >> 6;     // 0..7

  const int bid = blockIdx.x;
  const int t0  = (bid & 7)*512 + (bid >> 3)*NT;   // XCD-chunked, bijective

  int b, w0, h0;
  float v[3][8], tv[8];

  // prologue tile t0: register-path loads FIRST (pmax reduce hides under them)
  tile_decode(t0, b, w0, h0);
  q_load_full(x, b, w0, h0, tid, lane, wid, v, tv);

  // global-max reduce over 2048 partials (8KB, L2-resident)
  float4 pv = reinterpret_cast<const float4*>(pmax)[tid];
  float m = fmaxf(fmaxf(pv.x, pv.y), fmaxf(pv.z, pv.w));
  #pragma unroll
  for (int off = 32; off > 0; off >>= 1)
    m = fmaxf(m, __shfl_xor(m, off));
  if (lane == 0) redmax[wid] = m;
  __syncthreads();
  float gm = redmax[0];
  #pragma unroll
  for (int i = 1; i < 8; ++i) gm = fmaxf(gm, redmax[i]);

  const float s    = gm * 0.0078125f;   // max|x| / 128
  const float rinv = 1.0f / s;
  const float hs   = 0.5f * s;

  // loop-invariant A fragments, tap geometry, dequant constants
  const int g   = lane >> 4;
  const int tlg = g >> 1;
  int kr[5], kw[5];
  #pragma unroll
  for (int mm = 0; mm < 5; ++mm){
    int t = 2*mm + tlg; if (t > 8) t = 8;  // tap 9: A=0, read tap 8 (finite)
    kr[mm] = (t*11) >> 5;
    kw[mm] = t - kr[mm]*3;
  }
  s16x8 A[5];
  const s16x8* pA = reinterpret_cast<const s16x8*>(packA);
  #pragma unroll
  for (int mm = 0; mm < 5; ++mm) A[mm] = pA[mm*64 + lane];
  float sc[4], bb[4];
  #pragma unroll
  for (int j = 0; j < 4; ++j){
    sc[j] = s * sw[g*4 + j];
    bb[j] = bias[g*4 + j];
  }

  q_write_full(ldsq, tid, lane, wid, v, tv, rinv, s, hs);
  __syncthreads();

  // prologue DMA for tile t0+1
  {
    int b2, w2, h2; tile_decode(t0 + 1, b2, w2, h2);
    dma_stage16(x, b2, w2, h2, lane, wid, lds_raw);
  }

  for (int k = 0; k < NT; ++k){
    const int cur = k & 1;
    tile_decode(t0 + k, b, w0, h0);
    c_phase(ldsq, cur*BUFU, A, kr, kw, lane, wid, b, w0, h0, sc, bb, out);
    if (k < NT-1){
      int b2, w2, h2; tile_decode(t0 + k + 1, b2, w2, h2);
      const int nxt = (cur^1)*BUFU;
      __builtin_amdgcn_sched_barrier(0);
      asm volatile("s_waitcnt vmcnt(16)" ::: "memory");   // DMAs(k+1) done; 16 stores may fly
      asm volatile("s_waitcnt lgkmcnt(0)" ::: "memory");
      __builtin_amdgcn_s_barrier();                        // A: raw(k+1) visible to all waves
      __builtin_amdgcn_sched_barrier(0);

      const bool rowok = (h2 + wid + 1) < 256;
      u32 r[16];
      #pragma unroll
      for (int ci = 0; ci < 16; ++ci){
        int p = wid*16 + ci;
        r[ci] = (lane > 0) ? lds_raw[p*64 + (lane - 1)] : lds_raw[RAWB + p*2];
      }
      if (lane < 4)   // tail cols 64,65 quantized straight from raw (pre-A2)
        quant_pair(ldsq, nxt, lds_raw, wid, 64 + (lane >> 1), lane & 1, rowok, w2, rinv, s, hs);

      __builtin_amdgcn_sched_barrier(0);
      asm volatile("s_waitcnt lgkmcnt(0)" ::: "memory");
      __builtin_amdgcn_s_barrier();                        // A2: raw fully consumed
      __builtin_amdgcn_sched_barrier(0);

      if (k < NT-2){                                       // DMA(k+2): flies across B + next c_phase
        int b3, w3, h3; tile_decode(t0 + k + 2, b3, w3, h3);
        dma_stage16(x, b3, w3, h3, lane, wid, lds_raw);
      }
      __builtin_amdgcn_sched_barrier(0);

      // halo-row reuse: tile k rows 8,9 -> tile k+1 rows 0,1 (quant buf only)
      if (tid < 2*RSTR){
        int rr2 = tid >= RSTR;
        int cc2 = tid - rr2*RSTR;
        ldsq[nxt + rr2*RSTR + cc2] = ldsq[cur*BUFU + (8+rr2)*RSTR + cc2];
      }
      quant_main_regs(ldsq, nxt, r, lane, wid, w2, h2, rinv, s, hs);

      __builtin_amdgcn_sched_barrier(0);
      asm volatile("s_waitcnt lgkmcnt(0)" ::: "memory");
      __builtin_amdgcn_s_barrier();                        // B: nxt ready; DMA(k+2) still in flight
      __builtin_amdgcn_sched_barrier(0);
    }
  }
}

extern "C" void kernel_launch(void* const* d_in, const int* in_sizes, int n_in,
                              void* d_out, int out_size, void* d_ws, size_t ws_size,
                              hipStream_t stream){
  const float* x    = (const float*)d_in[0];
  const float* wq   = (const float*)d_in[1];
  const float* sw   = (const float*)d_in[2];
  const float* bias = (const float*)d_in[3];
  float* out = (float*)d_out;
  unsigned short* packA = (unsigned short*)((char*)d_ws + 64);
  float* pmax = (float*)((char*)d_ws + 8192);

  absmax_kernel<<<2048, 256, 0, stream>>>(x, wq, pmax, packA, (B_*16*H_*W_)/4);
  fconv_kernel<<<NTILES/NT, 512, 0, stream>>>(x, sw, bias, pmax, packA, out);
}